// Round 6
// baseline (654.851 us; speedup 1.0000x reference)
//
#include <hip/hip_runtime.h>

#define F1 128
#define F2 8
#define CAP 64       // fixed CSR capacity per node (deg ~ Poisson(16); P(>64) ~ 1e-20)
#define RA 1024      // nodes per range, k_degout
#define NCHUNK 8     // edge chunks, k_degout
#define RB 512       // nodes per range, k_bucketL

typedef unsigned short us8 __attribute__((ext_vector_type(8)));

__device__ inline unsigned short f2bf(float f) {
  unsigned u = __float_as_uint(f);
  u += 0x7FFF + ((u >> 16) & 1);   // round-to-nearest-even
  return (unsigned short)(u >> 16);
}
__device__ inline float bf2f(unsigned short h) {
  return __uint_as_float(((unsigned)h) << 16);
}

// ---------- pack indices to ushort (N < 65536), pad to 0xFFFF ----------
__global__ void k_pack(const int* __restrict__ src, const int* __restrict__ dst,
                       unsigned short* __restrict__ src16, unsigned short* __restrict__ dst16,
                       int E, int Epad) {
  int e = blockIdx.x * 256 + threadIdx.x;
  if (e < Epad) {
    src16[e] = (e < E) ? (unsigned short)src[e] : (unsigned short)0xFFFF;
    dst16[e] = (e < E) ? (unsigned short)dst[e] : (unsigned short)0xFFFF;
  }
}

// ---------- deg_out histogram: (range x chunk) blocks, LDS bins, zero global atomics ----------
__global__ __launch_bounds__(256) void k_degout(const unsigned short* __restrict__ src16,
                                                int* __restrict__ partial,
                                                int Epad, int Elen, int N) {
  __shared__ int bins[RA];
  int r = blockIdx.x;
  int c = blockIdx.y;
  int range0 = r * RA;
  int t = threadIdx.x;
  for (int i = t; i < RA; i += 256) bins[i] = 0;
  __syncthreads();
  int e0 = c * Elen;
  int e1 = min(e0 + Elen, Epad);
  for (int base = e0 + t * 8; base < e1; base += 256 * 8) {
    us8 v = *(const us8*)&src16[base];
#pragma unroll
    for (int j = 0; j < 8; ++j) {
      int sn = (int)v[j] - range0;
      if ((unsigned)sn < (unsigned)RA) atomicAdd(&bins[sn], 1);
    }
  }
  __syncthreads();
  for (int i = t; i < RA; i += 256) {
    int n = range0 + i;
    if (n < N) partial[c * N + n] = bins[i];
  }
}

// ---------- CSR build: one block per 512-node dst-range, LDS cursors, fixed-cap slots ----------
// Replaces degree-count(dst) + scan + bucket. cnt[n] = deg_in. Zero global atomics.
__global__ __launch_bounds__(256) void k_bucketL(const unsigned short* __restrict__ dst16,
                                                 const int* __restrict__ src,
                                                 int* __restrict__ esrc, int* __restrict__ cnt,
                                                 int Epad, int N) {
  __shared__ int cur[RB];
  int range0 = blockIdx.x * RB;
  int t = threadIdx.x;
  for (int i = t; i < RB; i += 256) cur[i] = 0;
  __syncthreads();
  for (int base = t * 8; base < Epad; base += 256 * 8) {
    us8 v = *(const us8*)&dst16[base];
#pragma unroll
    for (int j = 0; j < 8; ++j) {
      int dn = (int)v[j] - range0;
      if ((unsigned)dn < (unsigned)RB) {
        int p = atomicAdd(&cur[dn], 1);
        if (p < CAP) esrc[(range0 + dn) * CAP + p] = src[base + j];
      }
    }
  }
  __syncthreads();
  for (int i = t; i < RB; i += 256) {
    int n = range0 + i;
    if (n < N) cnt[n] = min(cur[i], CAP);
  }
}

// ---------- norms: sum deg_out partials; deg_in = cnt ----------
__global__ void k_norms(const int* __restrict__ partial, const int* __restrict__ cnt,
                        float* __restrict__ norm_src, float* __restrict__ norm_dst, int N) {
  int n = blockIdx.x * 256 + threadIdx.x;
  if (n < N) {
    int dout = 0;
#pragma unroll
    for (int c = 0; c < NCHUNK; ++c) dout += partial[c * N + n];
    int din = cnt[n];
    norm_src[n] = dout > 0 ? rsqrtf((float)dout) : 0.f;
    norm_dst[n] = din > 0 ? rsqrtf((float)din) : 0.f;
  }
}

// ---------- GEMM1: h1n[n][c] = bf16( (sum_k x[n][k] W1[k][c]) * norm_src[n] ) ----------
__global__ __launch_bounds__(256) void k_gemm1(const float* __restrict__ x,
                                               const float* __restrict__ W1,
                                               const float* __restrict__ norm_src,
                                               unsigned short* __restrict__ h1n, int N) {
  __shared__ float Wlds[128 * 64];   // [k][cc]
  __shared__ float xsT[128 * 64];    // [k][r]
  int row0 = blockIdx.x * 64;
  int c0 = blockIdx.y * 64;
  int tid = threadIdx.x;

  for (int i = tid; i < 2048; i += 256) {
    int k = i >> 4;
    int cc = (i & 15) << 2;
    *(float4*)&Wlds[k * 64 + cc] = *(const float4*)&W1[k * 128 + c0 + cc];
  }
  for (int i = tid; i < 2048; i += 256) {
    int r = i & 63;
    int kb = (i >> 6) << 2;
    int grow = row0 + r;
    float4 v = make_float4(0.f, 0.f, 0.f, 0.f);
    if (grow < N) v = *(const float4*)&x[(size_t)grow * 128 + kb];
    xsT[(kb + 0) * 64 + r] = v.x;
    xsT[(kb + 1) * 64 + r] = v.y;
    xsT[(kb + 2) * 64 + r] = v.z;
    xsT[(kb + 3) * 64 + r] = v.w;
  }
  __syncthreads();

  int tc = tid & 15;
  int tr = tid >> 4;
  float acc[4][4] = {{0.f}};
#pragma unroll 4
  for (int k = 0; k < 128; ++k) {
    float4 xv = *(const float4*)&xsT[k * 64 + tr * 4];
    float4 wv = *(const float4*)&Wlds[k * 64 + tc * 4];
    acc[0][0] += xv.x * wv.x; acc[0][1] += xv.x * wv.y; acc[0][2] += xv.x * wv.z; acc[0][3] += xv.x * wv.w;
    acc[1][0] += xv.y * wv.x; acc[1][1] += xv.y * wv.y; acc[1][2] += xv.y * wv.z; acc[1][3] += xv.y * wv.w;
    acc[2][0] += xv.z * wv.x; acc[2][1] += xv.z * wv.y; acc[2][2] += xv.z * wv.z; acc[2][3] += xv.z * wv.w;
    acc[3][0] += xv.w * wv.x; acc[3][1] += xv.w * wv.y; acc[3][2] += xv.w * wv.z; acc[3][3] += xv.w * wv.w;
  }
#pragma unroll
  for (int i = 0; i < 4; ++i) {
    int grow = row0 + tr * 4 + i;
    if (grow < N) {
      float ns = norm_src[grow];
      ushort4 o;
      o.x = f2bf(acc[i][0] * ns);
      o.y = f2bf(acc[i][1] * ns);
      o.z = f2bf(acc[i][2] * ns);
      o.w = f2bf(acc[i][3] * ns);
      *(ushort4*)&h1n[(size_t)grow * 128 + c0 + tc * 4] = o;
    }
  }
}

// ---------- layer-1 aggregation: one wave per dst node, 4 edges in flight ----------
__global__ __launch_bounds__(256) void k_agg1(const unsigned short* __restrict__ h1n,
                                              const int* __restrict__ cnt,
                                              const int* __restrict__ esrc,
                                              const float* __restrict__ norm_dst,
                                              const float* __restrict__ b1,
                                              float* __restrict__ h1b, int N) {
  int wid = (blockIdx.x * 256 + threadIdx.x) >> 6;
  int lane = threadIdx.x & 63;
  if (wid >= N) return;
  int i0 = wid * CAP;
  int i1 = i0 + cnt[wid];
  int q = lane >> 4;
  int fl = lane & 15;
  float acc[8] = {0.f, 0.f, 0.f, 0.f, 0.f, 0.f, 0.f, 0.f};
  for (int i = i0; i < i1; i += 64) {
    int cnt64 = min(64, i1 - i);
    int eid = (i + lane < i1) ? esrc[i + lane] : -1;
    for (int t = 0; t < cnt64; t += 4) {
      int s = __shfl(eid, t + q);
      if (s >= 0) {
        us8 v = *(const us8*)&h1n[(size_t)s * 128 + fl * 8];
#pragma unroll
        for (int j = 0; j < 8; ++j) acc[j] += bf2f(v[j]);
      }
    }
  }
#pragma unroll
  for (int j = 0; j < 8; ++j) acc[j] += __shfl_down(acc[j], 32);
#pragma unroll
  for (int j = 0; j < 8; ++j) acc[j] += __shfl_down(acc[j], 16);
  if (lane < 16) {
    float nd = norm_dst[wid];
    float4 b0 = *(const float4*)&b1[fl * 8];
    float4 b4 = *(const float4*)&b1[fl * 8 + 4];
    float4 o0, o4;
    o0.x = fmaxf(acc[0] * nd + b0.x, 0.f);
    o0.y = fmaxf(acc[1] * nd + b0.y, 0.f);
    o0.z = fmaxf(acc[2] * nd + b0.z, 0.f);
    o0.w = fmaxf(acc[3] * nd + b0.w, 0.f);
    o4.x = fmaxf(acc[4] * nd + b4.x, 0.f);
    o4.y = fmaxf(acc[5] * nd + b4.y, 0.f);
    o4.z = fmaxf(acc[6] * nd + b4.z, 0.f);
    o4.w = fmaxf(acc[7] * nd + b4.w, 0.f);
    *(float4*)&h1b[(size_t)wid * 128 + fl * 8] = o0;
    *(float4*)&h1b[(size_t)wid * 128 + fl * 8 + 4] = o4;
  }
}

// ---------- GEMM2 ----------
__global__ __launch_bounds__(256) void k_gemm2(const float* __restrict__ h1b,
                                               const float* __restrict__ W2,
                                               const float* __restrict__ norm_src,
                                               float* __restrict__ h2n, int N) {
  __shared__ float W2l[128 * 8];
  int tid = threadIdx.x;
  for (int i = tid; i < 1024; i += 256) W2l[i] = W2[i];
  __syncthreads();
  int g = blockIdx.x * 256 + tid;
  int node = g >> 3, j = g & 7;
  if (node >= N) return;
  const float* row = h1b + (size_t)node * 128;
  float acc = 0.f;
#pragma unroll
  for (int k = 0; k < 128; k += 4) {
    float4 v = *(const float4*)&row[k];
    acc += v.x * W2l[(k + 0) * 8 + j] + v.y * W2l[(k + 1) * 8 + j] +
           v.z * W2l[(k + 2) * 8 + j] + v.w * W2l[(k + 3) * 8 + j];
  }
  h2n[g] = acc * norm_src[node];
}

// ---------- layer-2 aggregation + mean-pool: LDS pre-reduction ----------
__global__ __launch_bounds__(256) void k_agg2pool(const float* __restrict__ h2n,
                                                  const int* __restrict__ cnt,
                                                  const int* __restrict__ esrc,
                                                  const float* __restrict__ norm_dst,
                                                  const float* __restrict__ b2,
                                                  const int* __restrict__ gids,
                                                  float* __restrict__ gsum, int N) {
  __shared__ float bins[16 * 8];
  __shared__ int sg0;
  int tid = threadIdx.x;
  if (tid < 128) bins[tid] = 0.f;
  int base = blockIdx.x * 32;
  if (tid == 0) sg0 = gids[min(base, N - 1)];
  __syncthreads();
  int node = base + (tid >> 3);
  int j = tid & 7;
  if (node < N) {
    int i0 = node * CAP;
    int i1 = i0 + cnt[node];
    float acc = 0.f;
    for (int i = i0; i < i1; i += 8) {
      int c8 = min(8, i1 - i);
      int eid = (i + j < i1) ? esrc[i + j] : 0;
      for (int t = 0; t < c8; ++t) {
        int s = __shfl(eid, t, 8);
        acc += h2n[s * 8 + j];
      }
    }
    float r = acc * norm_dst[node] + b2[j];
    int delta = gids[node] - sg0;
    if (delta < 16) atomicAdd(&bins[delta * 8 + j], r);
    else atomicAdd(&gsum[gids[node] * 8 + j], r);
  }
  __syncthreads();
  if (tid < 128) {
    float v = bins[tid];
    if (v != 0.f) atomicAdd(&gsum[(sg0 + (tid >> 3)) * 8 + (tid & 7)], v);
  }
}

// ---------- final ----------
__global__ void k_final(const float* __restrict__ gsum, const int* __restrict__ gids,
                        float* __restrict__ out, int NG, int N) {
  int i = blockIdx.x * 256 + threadIdx.x;
  if (i < NG * F2) {
    int g = i >> 3;
    int lo = 0, hi = N;
    while (lo < hi) { int m = (lo + hi) >> 1; if (gids[m] < g) lo = m + 1; else hi = m; }
    int lb = lo;
    lo = 0; hi = N;
    while (lo < hi) { int m = (lo + hi) >> 1; if (gids[m] <= g) lo = m + 1; else hi = m; }
    int cnt = lo - lb;
    out[i] = gsum[i] / fmaxf((float)cnt, 1.f);
  }
}

extern "C" void kernel_launch(void* const* d_in, const int* in_sizes, int n_in,
                              void* d_out, int out_size, void* d_ws, size_t ws_size,
                              hipStream_t stream) {
  const float* x  = (const float*)d_in[0];
  const float* W1 = (const float*)d_in[1];
  const float* b1 = (const float*)d_in[2];
  const float* W2 = (const float*)d_in[3];
  const float* b2 = (const float*)d_in[4];
  const int* src  = (const int*)d_in[5];
  const int* dst  = (const int*)d_in[6];
  const int* gids = (const int*)d_in[7];
  int N = in_sizes[0] / F1;
  int E = in_sizes[5];
  int NG = out_size / F2;
  float* out = (float*)d_out;

  int Epad = (E + 2047) & ~2047;                    // multiple of 256*8
  int Elen = ((Epad + NCHUNK - 1) / NCHUNK + 2047) & ~2047;
  int nrA = (N + RA - 1) / RA;
  int nrB = (N + RB - 1) / RB;

  char* p = (char*)d_ws;
  auto alloc = [&](size_t bytes) -> void* {
    void* r = (void*)p;
    p += (bytes + 255) & ~(size_t)255;
    return r;
  };
  float* gsum    = (float*)alloc((size_t)NG * F2 * 4);       // zeroed
  size_t zero_bytes = (size_t)((char*)p - (char*)gsum);
  unsigned short* src16 = (unsigned short*)alloc((size_t)Epad * 2);
  unsigned short* dst16 = (unsigned short*)alloc((size_t)Epad * 2);
  int* partial   = (int*)alloc((size_t)NCHUNK * N * 4);
  int* cnt       = (int*)alloc((size_t)N * 4);
  float* norm_src = (float*)alloc((size_t)N * 4);
  float* norm_dst = (float*)alloc((size_t)N * 4);
  int* esrc      = (int*)alloc((size_t)N * CAP * 4);
  unsigned short* h1n = (unsigned short*)alloc((size_t)N * F1 * 2);
  float* h1b     = (float*)alloc((size_t)N * F1 * 4);
  float* h2n     = (float*)alloc((size_t)N * F2 * 4);
  (void)ws_size; (void)n_in;

  hipMemsetAsync(gsum, 0, zero_bytes, stream);

  k_pack<<<(Epad + 255) / 256, 256, 0, stream>>>(src, dst, src16, dst16, E, Epad);
  k_degout<<<dim3(nrA, NCHUNK), 256, 0, stream>>>(src16, partial, Epad, Elen, N);
  k_bucketL<<<nrB, 256, 0, stream>>>(dst16, src, esrc, cnt, Epad, N);
  k_norms<<<(N + 255) / 256, 256, 0, stream>>>(partial, cnt, norm_src, norm_dst, N);
  k_gemm1<<<dim3((N + 63) / 64, 2), 256, 0, stream>>>(x, W1, norm_src, h1n, N);
  k_agg1<<<(N + 3) / 4, 256, 0, stream>>>(h1n, cnt, esrc, norm_dst, b1, h1b, N);
  k_gemm2<<<((size_t)N * 8 + 255) / 256, 256, 0, stream>>>(h1b, W2, norm_src, h2n, N);
  k_agg2pool<<<((N * 8 + 255) / 256), 256, 0, stream>>>(h2n, cnt, esrc, norm_dst, b2, gids, gsum, N);
  k_final<<<(NG * F2 + 255) / 256, 256, 0, stream>>>(gsum, gids, out, NG, N);
}

// Round 7
// 249.588 us; speedup vs baseline: 2.6237x; 2.6237x over previous
//
#include <hip/hip_runtime.h>

#define F1 128
#define F2 8
#define CAP 64       // fixed CSR capacity per node (deg ~ Poisson(16); P(>64) ~ 1e-20)
#define RH 8192      // nodes per range (32 KB LDS bins)
#define ECH 16384    // edges per chunk (multiple of 2048)

typedef unsigned short us8 __attribute__((ext_vector_type(8)));

__device__ inline unsigned short f2bf(float f) {
  unsigned u = __float_as_uint(f);
  u += 0x7FFF + ((u >> 16) & 1);   // round-to-nearest-even
  return (unsigned short)(u >> 16);
}
__device__ inline float bf2f(unsigned short h) {
  return __uint_as_float(((unsigned)h) << 16);
}

// ---------- pack indices to ushort (N < 65536), pad with 0xFFFF ----------
__global__ void k_pack(const int* __restrict__ src, const int* __restrict__ dst,
                       unsigned short* __restrict__ src16, unsigned short* __restrict__ dst16,
                       int E, int Epad) {
  int e = blockIdx.x * 256 + threadIdx.x;
  if (e < Epad) {
    src16[e] = (e < E) ? (unsigned short)src[e] : (unsigned short)0xFFFF;
    dst16[e] = (e < E) ? (unsigned short)dst[e] : (unsigned short)0xFFFF;
  }
}

// ---------- pass 1: per-(range,chunk) histograms of src AND dst, LDS-only atomics ----------
__global__ __launch_bounds__(256) void k_hist(const unsigned short* __restrict__ src16,
                                              const unsigned short* __restrict__ dst16,
                                              int* __restrict__ partialA,   // src hist [c][n]
                                              int* __restrict__ partialB,   // dst hist [c][n]
                                              int Epad, int N) {
  __shared__ int binsA[RH];
  __shared__ int binsB[RH];
  int range0 = blockIdx.x * RH;
  int c = blockIdx.y;
  int t = threadIdx.x;
  for (int i = t; i < RH; i += 256) { binsA[i] = 0; binsB[i] = 0; }
  __syncthreads();
  int e0 = c * ECH, e1 = min(e0 + ECH, Epad);
  for (int base = e0 + t * 8; base < e1; base += 2048) {
    us8 a = *(const us8*)&src16[base];
    us8 b = *(const us8*)&dst16[base];
#pragma unroll
    for (int j = 0; j < 8; ++j) {
      int sn = (int)a[j] - range0;
      if ((unsigned)sn < (unsigned)RH) atomicAdd(&binsA[sn], 1);
      int dn = (int)b[j] - range0;
      if ((unsigned)dn < (unsigned)RH) atomicAdd(&binsB[dn], 1);
    }
  }
  __syncthreads();
  for (int i = t; i < RH; i += 256) {
    int n = range0 + i;
    if (n < N) {
      partialA[c * N + n] = binsA[i];
      partialB[c * N + n] = binsB[i];
    }
  }
}

// ---------- per-node chunk-prefix starts + cnt + norms (no global scan needed) ----------
__global__ void k_starts(const int* __restrict__ partialA, const int* __restrict__ partialB,
                         int* __restrict__ starts, int* __restrict__ cnt,
                         float* __restrict__ norm_src, float* __restrict__ norm_dst,
                         int N, int NCH) {
  int n = blockIdx.x * 256 + threadIdx.x;
  if (n < N) {
    int dout = 0;
    for (int c = 0; c < NCH; ++c) dout += partialA[c * N + n];
    int run = n * CAP;
    for (int c = 0; c < NCH; ++c) {
      starts[c * N + n] = run;
      run += partialB[c * N + n];
    }
    int din = run - n * CAP;
    cnt[n] = min(din, CAP);
    norm_src[n] = dout > 0 ? rsqrtf((float)dout) : 0.f;
    norm_dst[n] = din > 0 ? rsqrtf((float)din) : 0.f;
  }
}

// ---------- pass 2: scatter into fixed-cap CSR via LDS cursors seeded from starts ----------
__global__ __launch_bounds__(256) void k_scatter(const unsigned short* __restrict__ src16,
                                                 const unsigned short* __restrict__ dst16,
                                                 const int* __restrict__ starts,
                                                 unsigned short* __restrict__ esrc16,
                                                 int Epad, int N) {
  __shared__ int cur[RH];
  int range0 = blockIdx.x * RH;
  int c = blockIdx.y;
  int t = threadIdx.x;
  for (int i = t; i < RH; i += 256) {
    int n = range0 + i;
    cur[i] = (n < N) ? starts[c * N + n] : 0;
  }
  __syncthreads();
  int e0 = c * ECH, e1 = min(e0 + ECH, Epad);
  for (int base = e0 + t * 8; base < e1; base += 2048) {
    us8 a = *(const us8*)&src16[base];
    us8 b = *(const us8*)&dst16[base];
#pragma unroll
    for (int j = 0; j < 8; ++j) {
      int dn = (int)b[j] - range0;
      if ((unsigned)dn < (unsigned)RH) {
        int node = range0 + dn;
        int p = atomicAdd(&cur[dn], 1);
        if (p < (node + 1) * CAP) esrc16[p] = a[j];
      }
    }
  }
}

// ---------- GEMM1: h1n[n][c] = bf16( (sum_k x[n][k] W1[k][c]) * norm_src[n] ) ----------
__global__ __launch_bounds__(256) void k_gemm1(const float* __restrict__ x,
                                               const float* __restrict__ W1,
                                               const float* __restrict__ norm_src,
                                               unsigned short* __restrict__ h1n, int N) {
  __shared__ float Wlds[128 * 64];   // [k][cc]
  __shared__ float xsT[128 * 64];    // [k][r]
  int row0 = blockIdx.x * 64;
  int c0 = blockIdx.y * 64;
  int tid = threadIdx.x;

  for (int i = tid; i < 2048; i += 256) {
    int k = i >> 4;
    int cc = (i & 15) << 2;
    *(float4*)&Wlds[k * 64 + cc] = *(const float4*)&W1[k * 128 + c0 + cc];
  }
  for (int i = tid; i < 2048; i += 256) {
    int r = i & 63;
    int kb = (i >> 6) << 2;
    int grow = row0 + r;
    float4 v = make_float4(0.f, 0.f, 0.f, 0.f);
    if (grow < N) v = *(const float4*)&x[(size_t)grow * 128 + kb];
    xsT[(kb + 0) * 64 + r] = v.x;
    xsT[(kb + 1) * 64 + r] = v.y;
    xsT[(kb + 2) * 64 + r] = v.z;
    xsT[(kb + 3) * 64 + r] = v.w;
  }
  __syncthreads();

  int tc = tid & 15;
  int tr = tid >> 4;
  float acc[4][4] = {{0.f}};
#pragma unroll 4
  for (int k = 0; k < 128; ++k) {
    float4 xv = *(const float4*)&xsT[k * 64 + tr * 4];
    float4 wv = *(const float4*)&Wlds[k * 64 + tc * 4];
    acc[0][0] += xv.x * wv.x; acc[0][1] += xv.x * wv.y; acc[0][2] += xv.x * wv.z; acc[0][3] += xv.x * wv.w;
    acc[1][0] += xv.y * wv.x; acc[1][1] += xv.y * wv.y; acc[1][2] += xv.y * wv.z; acc[1][3] += xv.y * wv.w;
    acc[2][0] += xv.z * wv.x; acc[2][1] += xv.z * wv.y; acc[2][2] += xv.z * wv.z; acc[2][3] += xv.z * wv.w;
    acc[3][0] += xv.w * wv.x; acc[3][1] += xv.w * wv.y; acc[3][2] += xv.w * wv.z; acc[3][3] += xv.w * wv.w;
  }
#pragma unroll
  for (int i = 0; i < 4; ++i) {
    int grow = row0 + tr * 4 + i;
    if (grow < N) {
      float ns = norm_src[grow];
      ushort4 o;
      o.x = f2bf(acc[i][0] * ns);
      o.y = f2bf(acc[i][1] * ns);
      o.z = f2bf(acc[i][2] * ns);
      o.w = f2bf(acc[i][3] * ns);
      *(ushort4*)&h1n[(size_t)grow * 128 + c0 + tc * 4] = o;
    }
  }
}

// ---------- layer-1 aggregation: one wave per dst node, 4 edges in flight ----------
__global__ __launch_bounds__(256) void k_agg1(const unsigned short* __restrict__ h1n,
                                              const int* __restrict__ cnt,
                                              const unsigned short* __restrict__ esrc16,
                                              const float* __restrict__ norm_dst,
                                              const float* __restrict__ b1,
                                              float* __restrict__ h1b, int N) {
  int wid = (blockIdx.x * 256 + threadIdx.x) >> 6;
  int lane = threadIdx.x & 63;
  if (wid >= N) return;
  int i0 = wid * CAP;
  int i1 = i0 + cnt[wid];
  int q = lane >> 4;
  int fl = lane & 15;
  float acc[8] = {0.f, 0.f, 0.f, 0.f, 0.f, 0.f, 0.f, 0.f};
  for (int i = i0; i < i1; i += 64) {
    int cnt64 = min(64, i1 - i);
    int eid = (i + lane < i1) ? (int)esrc16[i + lane] : -1;
    for (int t = 0; t < cnt64; t += 4) {
      int s = __shfl(eid, t + q);
      if (s >= 0) {
        us8 v = *(const us8*)&h1n[(size_t)s * 128 + fl * 8];
#pragma unroll
        for (int j = 0; j < 8; ++j) acc[j] += bf2f(v[j]);
      }
    }
  }
#pragma unroll
  for (int j = 0; j < 8; ++j) acc[j] += __shfl_down(acc[j], 32);
#pragma unroll
  for (int j = 0; j < 8; ++j) acc[j] += __shfl_down(acc[j], 16);
  if (lane < 16) {
    float nd = norm_dst[wid];
    float4 b0 = *(const float4*)&b1[fl * 8];
    float4 b4 = *(const float4*)&b1[fl * 8 + 4];
    float4 o0, o4;
    o0.x = fmaxf(acc[0] * nd + b0.x, 0.f);
    o0.y = fmaxf(acc[1] * nd + b0.y, 0.f);
    o0.z = fmaxf(acc[2] * nd + b0.z, 0.f);
    o0.w = fmaxf(acc[3] * nd + b0.w, 0.f);
    o4.x = fmaxf(acc[4] * nd + b4.x, 0.f);
    o4.y = fmaxf(acc[5] * nd + b4.y, 0.f);
    o4.z = fmaxf(acc[6] * nd + b4.z, 0.f);
    o4.w = fmaxf(acc[7] * nd + b4.w, 0.f);
    *(float4*)&h1b[(size_t)wid * 128 + fl * 8] = o0;
    *(float4*)&h1b[(size_t)wid * 128 + fl * 8 + 4] = o4;
  }
}

// ---------- GEMM2 ----------
__global__ __launch_bounds__(256) void k_gemm2(const float* __restrict__ h1b,
                                               const float* __restrict__ W2,
                                               const float* __restrict__ norm_src,
                                               float* __restrict__ h2n, int N) {
  __shared__ float W2l[128 * 8];
  int tid = threadIdx.x;
  for (int i = tid; i < 1024; i += 256) W2l[i] = W2[i];
  __syncthreads();
  int g = blockIdx.x * 256 + tid;
  int node = g >> 3, j = g & 7;
  if (node >= N) return;
  const float* row = h1b + (size_t)node * 128;
  float acc = 0.f;
#pragma unroll
  for (int k = 0; k < 128; k += 4) {
    float4 v = *(const float4*)&row[k];
    acc += v.x * W2l[(k + 0) * 8 + j] + v.y * W2l[(k + 1) * 8 + j] +
           v.z * W2l[(k + 2) * 8 + j] + v.w * W2l[(k + 3) * 8 + j];
  }
  h2n[g] = acc * norm_src[node];
}

// ---------- layer-2 aggregation + mean-pool: LDS pre-reduction ----------
__global__ __launch_bounds__(256) void k_agg2pool(const float* __restrict__ h2n,
                                                  const int* __restrict__ cnt,
                                                  const unsigned short* __restrict__ esrc16,
                                                  const float* __restrict__ norm_dst,
                                                  const float* __restrict__ b2,
                                                  const int* __restrict__ gids,
                                                  float* __restrict__ gsum, int N) {
  __shared__ float bins[16 * 8];
  __shared__ int sg0;
  int tid = threadIdx.x;
  if (tid < 128) bins[tid] = 0.f;
  int base = blockIdx.x * 32;
  if (tid == 0) sg0 = gids[min(base, N - 1)];
  __syncthreads();
  int node = base + (tid >> 3);
  int j = tid & 7;
  if (node < N) {
    int i0 = node * CAP;
    int i1 = i0 + cnt[node];
    float acc = 0.f;
    for (int i = i0; i < i1; i += 8) {
      int c8 = min(8, i1 - i);
      int eid = (i + j < i1) ? (int)esrc16[i + j] : 0;
      for (int t = 0; t < c8; ++t) {
        int s = __shfl(eid, t, 8);
        acc += h2n[s * 8 + j];
      }
    }
    float r = acc * norm_dst[node] + b2[j];
    int delta = gids[node] - sg0;
    if (delta < 16) atomicAdd(&bins[delta * 8 + j], r);
    else atomicAdd(&gsum[gids[node] * 8 + j], r);
  }
  __syncthreads();
  if (tid < 128) {
    float v = bins[tid];
    if (v != 0.f) atomicAdd(&gsum[(sg0 + (tid >> 3)) * 8 + (tid & 7)], v);
  }
}

// ---------- final ----------
__global__ void k_final(const float* __restrict__ gsum, const int* __restrict__ gids,
                        float* __restrict__ out, int NG, int N) {
  int i = blockIdx.x * 256 + threadIdx.x;
  if (i < NG * F2) {
    int g = i >> 3;
    int lo = 0, hi = N;
    while (lo < hi) { int m = (lo + hi) >> 1; if (gids[m] < g) lo = m + 1; else hi = m; }
    int lb = lo;
    lo = 0; hi = N;
    while (lo < hi) { int m = (lo + hi) >> 1; if (gids[m] <= g) lo = m + 1; else hi = m; }
    int cnt = lo - lb;
    out[i] = gsum[i] / fmaxf((float)cnt, 1.f);
  }
}

extern "C" void kernel_launch(void* const* d_in, const int* in_sizes, int n_in,
                              void* d_out, int out_size, void* d_ws, size_t ws_size,
                              hipStream_t stream) {
  const float* x  = (const float*)d_in[0];
  const float* W1 = (const float*)d_in[1];
  const float* b1 = (const float*)d_in[2];
  const float* W2 = (const float*)d_in[3];
  const float* b2 = (const float*)d_in[4];
  const int* src  = (const int*)d_in[5];
  const int* dst  = (const int*)d_in[6];
  const int* gids = (const int*)d_in[7];
  int N = in_sizes[0] / F1;
  int E = in_sizes[5];
  int NG = out_size / F2;
  float* out = (float*)d_out;

  int Epad = (E + 2047) & ~2047;            // multiple of 256*8
  int NR  = (N + RH - 1) / RH;              // node ranges
  int NCH = (Epad + ECH - 1) / ECH;         // edge chunks

  char* p = (char*)d_ws;
  auto alloc = [&](size_t bytes) -> void* {
    void* r = (void*)p;
    p += (bytes + 255) & ~(size_t)255;
    return r;
  };
  float* gsum    = (float*)alloc((size_t)NG * F2 * 4);       // zeroed
  size_t zero_bytes = (size_t)((char*)p - (char*)gsum);
  unsigned short* src16 = (unsigned short*)alloc((size_t)Epad * 2);
  unsigned short* dst16 = (unsigned short*)alloc((size_t)Epad * 2);
  int* cnt       = (int*)alloc((size_t)N * 4);
  float* norm_src = (float*)alloc((size_t)N * 4);
  float* norm_dst = (float*)alloc((size_t)N * 4);
  unsigned short* esrc16 = (unsigned short*)alloc((size_t)N * CAP * 2);
  unsigned short* h1n = (unsigned short*)alloc((size_t)N * F1 * 2);
  float* h1b     = (float*)alloc((size_t)N * F1 * 4);
  float* h2n     = (float*)alloc((size_t)N * F2 * 4);
  // partialA/B + starts alias the h1n+h1b region (dead before gemm1/agg1 write it):
  // 3 * NCH * N * 4 = ~29.4 MB  <=  h1n (12.8 MB) + h1b (25.6 MB)
  int* partialA  = (int*)h1n;
  int* partialB  = partialA + (size_t)NCH * N;
  int* starts    = partialB + (size_t)NCH * N;
  (void)ws_size; (void)n_in;

  hipMemsetAsync(gsum, 0, zero_bytes, stream);

  k_pack<<<(Epad + 255) / 256, 256, 0, stream>>>(src, dst, src16, dst16, E, Epad);
  k_hist<<<dim3(NR, NCH), 256, 0, stream>>>(src16, dst16, partialA, partialB, Epad, N);
  k_starts<<<(N + 255) / 256, 256, 0, stream>>>(partialA, partialB, starts, cnt,
                                                norm_src, norm_dst, N, NCH);
  k_scatter<<<dim3(NR, NCH), 256, 0, stream>>>(src16, dst16, starts, esrc16, Epad, N);
  k_gemm1<<<dim3((N + 63) / 64, 2), 256, 0, stream>>>(x, W1, norm_src, h1n, N);
  k_agg1<<<(N + 3) / 4, 256, 0, stream>>>(h1n, cnt, esrc16, norm_dst, b1, h1b, N);
  k_gemm2<<<((size_t)N * 8 + 255) / 256, 256, 0, stream>>>(h1b, W2, norm_src, h2n, N);
  k_agg2pool<<<((N * 8 + 255) / 256), 256, 0, stream>>>(h2n, cnt, esrc16, norm_dst, b2, gids, gsum, N);
  k_final<<<(NG * F2 + 255) / 256, 256, 0, stream>>>(gsum, gids, out, NG, N);
}